// Round 7
// baseline (244.417 us; speedup 1.0000x reference)
//
#include <hip/hip_runtime.h>

#define B_ 2
#define N_ 6
#define D_ 41
#define H_ 16
#define W_ 44
#define C_ 64
#define X_ 200
#define Y_ 200
#define NPTS (B_*N_*D_*H_*W_)   // 346368
#define NBN (B_*N_)             // 12
#define NCELL (B_*X_*Y_)        // 80000
#define MAT_STRIDE 24           // doubles per (b,n)
#define CHUNK 32                // sorted points per wave in gather
#define NBLK_SCAN ((NCELL+255)/256)  // 313

__device__ inline void atomic_add_hw(float* p, float v) {
    unsafeAtomicAdd(p, v);
}

__device__ inline void inv3x3(const double m[9], double out[9]) {
    double a=m[0],b=m[1],c=m[2],d=m[3],e=m[4],f=m[5],g=m[6],h=m[7],i=m[8];
    double A  =  (e*i - f*h);
    double Bm = -(d*i - f*g);
    double Cm =  (d*h - e*g);
    double det = a*A + b*Bm + c*Cm;
    double id = 1.0/det;
    out[0] = A*id;   out[1] = -(b*i - c*h)*id; out[2] =  (b*f - c*e)*id;
    out[3] = Bm*id;  out[4] =  (a*i - c*g)*id; out[5] = -(a*f - c*d)*id;
    out[6] = Cm*id;  out[7] = -(a*h - b*g)*id; out[8] =  (a*e - b*d)*id;
}

// One thread per (b,n): inv(post_rots), comb = rot(inv(extr)) @ inv(K), trans.
// 4x4 inverse via closed-form adjugate (static indexing -> registers, no scratch).
__global__ void prep_kernel(const float* __restrict__ post_rots,
                            const float* __restrict__ intr,
                            const float* __restrict__ extr,
                            double* __restrict__ mats) {
    int bn = threadIdx.x;
    if (bn >= NBN) return;

    double pr[9], prinv[9], kk[9], kin[9];
    for (int i=0;i<9;i++) pr[i] = (double)post_rots[bn*9+i];
    inv3x3(pr, prinv);
    for (int i=0;i<9;i++) kk[i] = (double)intr[bn*9+i];
    inv3x3(kk, kin);

    const float* E = extr + bn*16;
    double a00=E[0], a01=E[1], a02=E[2], a03=E[3];
    double a10=E[4], a11=E[5], a12=E[6], a13=E[7];
    double a20=E[8], a21=E[9], a22=E[10], a23=E[11];
    double a30=E[12], a31=E[13], a32=E[14], a33=E[15];

    double s0=a00*a11-a10*a01, s1=a00*a12-a10*a02, s2=a00*a13-a10*a03;
    double s3=a01*a12-a11*a02, s4=a01*a13-a11*a03, s5=a02*a13-a12*a03;
    double c5=a22*a33-a32*a23, c4=a21*a33-a31*a23, c3=a21*a32-a31*a22;
    double c2=a20*a33-a30*a23, c1=a20*a32-a30*a22, c0=a20*a31-a30*a21;
    double det = s0*c5 - s1*c4 + s2*c3 + s3*c2 - s4*c1 + s5*c0;
    double iv = 1.0/det;

    double rot[9], trans[3];
    rot[0] = ( a11*c5 - a12*c4 + a13*c3)*iv;
    rot[1] = (-a01*c5 + a02*c4 - a03*c3)*iv;
    rot[2] = ( a31*s5 - a32*s4 + a33*s3)*iv;
    trans[0]=(-a21*s5 + a22*s4 - a23*s3)*iv;
    rot[3] = (-a10*c5 + a12*c2 - a13*c1)*iv;
    rot[4] = ( a00*c5 - a02*c2 + a03*c1)*iv;
    rot[5] = (-a30*s5 + a32*s2 - a33*s1)*iv;
    trans[1]=( a20*s5 - a22*s2 + a23*s1)*iv;
    rot[6] = ( a10*c4 - a11*c2 + a13*c0)*iv;
    rot[7] = (-a00*c4 + a01*c2 - a03*c0)*iv;
    rot[8] = ( a30*s4 - a31*s2 + a33*s0)*iv;
    trans[2]=(-a20*s4 + a21*s2 - a23*s0)*iv;

    double comb[9];
    for (int i=0;i<3;i++) for (int j=0;j<3;j++)
        comb[i*3+j] = rot[i*3+0]*kin[0+j] + rot[i*3+1]*kin[3+j] + rot[i*3+2]*kin[6+j];

    double* o = mats + (size_t)bn*MAT_STRIDE;
    for (int i=0;i<9;i++) o[i]   = prinv[i];
    for (int i=0;i<9;i++) o[9+i] = comb[i];
    for (int i=0;i<3;i++) o[18+i]= trans[i];
}

// One THREAD per point: cell id (or -1) + histogram.
__global__ __launch_bounds__(256)
void geom_kernel(const float* __restrict__ post_trans,
                 const float* __restrict__ frustum,
                 const float* __restrict__ bev_res,
                 const float* __restrict__ bev_start,
                 const double* __restrict__ mats,
                 int* __restrict__ rank, int* __restrict__ hist) {
    int p = blockIdx.x * blockDim.x + threadIdx.x;
    if (p >= NPTS) return;

    int w = p % W_; int t = p / W_;
    int h = t % H_;  t /= H_;
    int d = t % D_;  t /= D_;
    int bn = t;      int b = bn / N_;

    const double* M = mats + (size_t)bn*MAT_STRIDE;
    int fidx = ((d*H_ + h)*W_ + w)*3;
    double fx = (double)frustum[fidx+0];
    double fy = (double)frustum[fidx+1];
    double fz = (double)frustum[fidx+2];

    double px = fx - (double)post_trans[bn*3+0];
    double py = fy - (double)post_trans[bn*3+1];
    double pz = fz - (double)post_trans[bn*3+2];

    double q0 = M[0]*px + M[1]*py + M[2]*pz;
    double q1 = M[3]*px + M[4]*py + M[5]*pz;
    double q2 = M[6]*px + M[7]*py + M[8]*pz;

    double r0 = q0*q2, r1 = q1*q2, r2 = q2;

    double gx = M[9]*r0  + M[10]*r1 + M[11]*r2 + M[18];
    double gy = M[12]*r0 + M[13]*r1 + M[14]*r2 + M[19];
    double gz = M[15]*r0 + M[16]*r1 + M[17]*r2 + M[20];

    double resx = (double)bev_res[0], resy = (double)bev_res[1], resz = (double)bev_res[2];
    double sx = (double)bev_start[0] - resx*0.5;
    double sy = (double)bev_start[1] - resy*0.5;
    double sz = (double)bev_start[2] - resz*0.5;

    int cx = (int)((gx - sx)/resx);
    int cy = (int)((gy - sy)/resy);
    int cz = (int)((gz - sz)/resz);

    int cell = -1;
    if (cx >= 0 && cx < X_ && cy >= 0 && cy < Y_ && cz == 0) {
        cell = (b*X_ + cx)*Y_ + cy;
        atomicAdd(&hist[cell], 1);
    }
    rank[p] = cell;
}

// ---- 3-level hierarchical scan of hist[NCELL] -> offs/cursor ----
__global__ __launch_bounds__(256)
void scanA_kernel(const int* __restrict__ hist, int* __restrict__ bsum) {
    __shared__ int s[256];
    int i = blockIdx.x * 256 + threadIdx.x;
    s[threadIdx.x] = (i < NCELL) ? hist[i] : 0;
    __syncthreads();
    for (int o = 128; o > 0; o >>= 1) {
        if (threadIdx.x < o) s[threadIdx.x] += s[threadIdx.x + o];
        __syncthreads();
    }
    if (threadIdx.x == 0) bsum[blockIdx.x] = s[0];
}

__global__ __launch_bounds__(512)
void scanB_kernel(const int* __restrict__ bsum,
                  int* __restrict__ bofs, int* __restrict__ total_out) {
    __shared__ int s[512];
    int t = threadIdx.x;
    int v = (t < NBLK_SCAN) ? bsum[t] : 0;
    s[t] = v;
    __syncthreads();
    for (int o = 1; o < 512; o <<= 1) {
        int add = (t >= o) ? s[t - o] : 0;
        __syncthreads();
        s[t] += add;
        __syncthreads();
    }
    if (t < NBLK_SCAN) bofs[t] = s[t] - v;       // exclusive
    if (t == 511) *total_out = s[511];           // grand total
}

__global__ __launch_bounds__(256)
void scanC_kernel(const int* __restrict__ hist, const int* __restrict__ bofs,
                  int* __restrict__ offs, int* __restrict__ cursor) {
    __shared__ int s[256];
    int i = blockIdx.x * 256 + threadIdx.x;
    int v = (i < NCELL) ? hist[i] : 0;
    s[threadIdx.x] = v;
    __syncthreads();
    for (int o = 1; o < 256; o <<= 1) {
        int add = (threadIdx.x >= o) ? s[threadIdx.x - o] : 0;
        __syncthreads();
        s[threadIdx.x] += add;
        __syncthreads();
    }
    if (i < NCELL) {
        int excl = s[threadIdx.x] - v + bofs[blockIdx.x];
        offs[i] = excl;
        cursor[i] = excl;
    }
}

// Permute the FEATURE ROWS into sorted-by-cell order (one wave per point).
// Reads sequential (p = wave index); writes random 256B-contiguous (fire-and-forget).
__global__ __launch_bounds__(256)
void fill2_kernel(const float* __restrict__ feat,
                  const int* __restrict__ rank,
                  int* __restrict__ cursor,
                  float* __restrict__ sfeat,
                  int* __restrict__ clist) {
    int tid = blockIdx.x * blockDim.x + threadIdx.x;
    int p = tid >> 6, lane = tid & 63;
    if (p >= NPTS) return;
    int cell = rank[p];
    if (cell < 0) return;
    int pos = 0;
    if (lane == 0) pos = atomicAdd(&cursor[cell], 1);
    pos = __shfl(pos, 0);
    sfeat[(size_t)pos*C_ + lane] = feat[(size_t)p*C_ + lane];
    if (lane == 0) clist[pos] = cell;
}

// Segmented reduction over the SORTED feature array: reads fully sequential.
__global__ __launch_bounds__(256)
void gather3_kernel(const float* __restrict__ sfeat,
                    const int* __restrict__ clist,
                    const int* __restrict__ total_ptr,
                    float* __restrict__ out) {
    int gwave = (int)((blockIdx.x * blockDim.x + threadIdx.x) >> 6);
    int lane  = threadIdx.x & 63;
    int total = total_ptr[0];
    int i0 = gwave * CHUNK;
    if (i0 >= total) return;
    int n = min(CHUNK, total - i0);

    int cl = (lane < n) ? clist[i0 + lane] : -1;

    // Phase 1: sequential streaming loads (rows i0..i0+31), statically indexed.
    float v[CHUNK];
    #pragma unroll
    for (int i = 0; i < CHUNK; ++i) {
        v[i] = sfeat[(size_t)(i0 + i)*C_ + lane];   // in-bounds of sfeat[NPTS]; unused if i>=n
    }

    // Phase 2: segmented reduce over sorted cells, flush on change.
    int cur = __shfl(cl, 0);
    float acc = 0.f;
    #pragma unroll
    for (int i = 0; i < CHUNK; ++i) {
        if (i >= n) break;
        int cell = __shfl(cl, i);
        if (cell != cur) {
            int b = cur / (X_*Y_), xy = cur % (X_*Y_);
            atomic_add_hw(&out[((size_t)(b*C_ + lane))*(X_*Y_) + xy], acc);
            acc = 0.f; cur = cell;
        }
        acc += v[i];
    }
    int b = cur / (X_*Y_), xy = cur % (X_*Y_);
    atomic_add_hw(&out[((size_t)(b*C_ + lane))*(X_*Y_) + xy], acc);
}

// Fallback (tiny ws): direct atomics into (B,C,X,Y).
__global__ __launch_bounds__(256)
void scatter_fallback(const float* __restrict__ feat,
                      const int* __restrict__ rank,
                      float* __restrict__ dst) {
    int tid  = blockIdx.x * blockDim.x + threadIdx.x;
    int wave = tid >> 6;
    int lane = tid & 63;
    if (wave >= NPTS) return;
    int cell = rank[wave];
    if (cell < 0) return;
    int b = cell / (X_*Y_);
    int xy = cell % (X_*Y_);
    float v = feat[(size_t)wave*C_ + lane];
    atomic_add_hw(&dst[((size_t)(b*C_ + lane))*(X_*Y_) + xy], v);
}

extern "C" void kernel_launch(void* const* d_in, const int* in_sizes, int n_in,
                              void* d_out, int out_size, void* d_ws, size_t ws_size,
                              hipStream_t stream) {
    const float* feat       = (const float*)d_in[0];
    const float* post_trans = (const float*)d_in[1];
    const float* post_rots  = (const float*)d_in[2];
    const float* intr       = (const float*)d_in[3];
    const float* extr       = (const float*)d_in[4];
    const float* frustum    = (const float*)d_in[5];
    const float* bev_res    = (const float*)d_in[6];
    const float* bev_start  = (const float*)d_in[7];
    float* out = (float*)d_out;

    // ws layout
    char* base = (char*)d_ws;
    double* mats  = (double*)base;                         size_t off = 4096;
    int* rank     = (int*)(base + off);                    off += (size_t)NPTS*4;
    int* hist     = (int*)(base + off);                    off += (size_t)NCELL*4;
    int* offs     = (int*)(base + off);                    off += (size_t)(NCELL+1)*4 + 4;
    int* cursor   = (int*)(base + off);                    off += (size_t)NCELL*4;
    int* clist    = (int*)(base + off);                    off += (size_t)NPTS*4;
    int* bsum     = (int*)(base + off);                    off += 512*4;
    int* bofs     = (int*)(base + off);                    off += 512*4;
    off = (off + 511) & ~(size_t)511;
    float* sfeat  = (float*)(base + off);                  off += (size_t)NPTS*C_*4; // 88.7 MB
    bool have_ws = (ws_size >= off);

    hipLaunchKernelGGL(prep_kernel, dim3(1), dim3(16), 0, stream,
                       post_rots, intr, extr, mats);

    const int pt_blocks = (NPTS + 255) / 256;

    hipMemsetAsync(out, 0, (size_t)out_size*sizeof(float), stream);

    if (have_ws) {
        hipMemsetAsync(hist, 0, (size_t)NCELL*4, stream);
        geom_kernel<<<pt_blocks, 256, 0, stream>>>(post_trans, frustum, bev_res,
                                                   bev_start, mats, rank, hist);
        scanA_kernel<<<NBLK_SCAN, 256, 0, stream>>>(hist, bsum);
        scanB_kernel<<<1, 512, 0, stream>>>(bsum, bofs, &offs[NCELL]);
        scanC_kernel<<<NBLK_SCAN, 256, 0, stream>>>(hist, bofs, offs, cursor);
        const int f2_blocks = (NPTS*64 + 255) / 256;      // one wave per point
        fill2_kernel<<<f2_blocks, 256, 0, stream>>>(feat, rank, cursor, sfeat, clist);
        const int nchunks = (NPTS + CHUNK - 1) / CHUNK;   // 10824
        const int gblocks = (nchunks * 64 + 255) / 256;
        gather3_kernel<<<gblocks, 256, 0, stream>>>(sfeat, clist, &offs[NCELL], out);
    } else {
        geom_kernel<<<pt_blocks, 256, 0, stream>>>(post_trans, frustum, bev_res,
                                                   bev_start, mats, rank, hist);
        scatter_fallback<<<(NPTS*64 + 255)/256, 256, 0, stream>>>(feat, rank, out);
    }
}

// Round 8
// 125.195 us; speedup vs baseline: 1.9523x; 1.9523x over previous
//
#include <hip/hip_runtime.h>

#define B_ 2
#define N_ 6
#define D_ 41
#define H_ 16
#define W_ 44
#define C_ 64
#define X_ 200
#define Y_ 200
#define NPTS (B_*N_*D_*H_*W_)   // 346368
#define NBN (B_*N_)             // 12
#define NCELL (B_*X_*Y_)        // 80000
#define MAT_STRIDE 24           // doubles per (b,n)

__device__ inline void inv3x3(const double m[9], double out[9]) {
    double a=m[0],b=m[1],c=m[2],d=m[3],e=m[4],f=m[5],g=m[6],h=m[7],i=m[8];
    double A  =  (e*i - f*h);
    double Bm = -(d*i - f*g);
    double Cm =  (d*h - e*g);
    double det = a*A + b*Bm + c*Cm;
    double id = 1.0/det;
    out[0] = A*id;   out[1] = -(b*i - c*h)*id; out[2] =  (b*f - c*e)*id;
    out[3] = Bm*id;  out[4] =  (a*i - c*g)*id; out[5] = -(a*f - c*d)*id;
    out[6] = Cm*id;  out[7] = -(a*h - b*g)*id; out[8] =  (a*e - b*d)*id;
}

// One thread per (b,n): inv(post_rots), comb = rot(inv(extr)) @ inv(K), trans.
// 4x4 inverse via closed-form adjugate (static indexing -> registers, no scratch).
__global__ void prep_kernel(const float* __restrict__ post_rots,
                            const float* __restrict__ intr,
                            const float* __restrict__ extr,
                            double* __restrict__ mats) {
    int bn = threadIdx.x;
    if (bn >= NBN) return;

    double pr[9], prinv[9], kk[9], kin[9];
    for (int i=0;i<9;i++) pr[i] = (double)post_rots[bn*9+i];
    inv3x3(pr, prinv);
    for (int i=0;i<9;i++) kk[i] = (double)intr[bn*9+i];
    inv3x3(kk, kin);

    const float* E = extr + bn*16;
    double a00=E[0], a01=E[1], a02=E[2], a03=E[3];
    double a10=E[4], a11=E[5], a12=E[6], a13=E[7];
    double a20=E[8], a21=E[9], a22=E[10], a23=E[11];
    double a30=E[12], a31=E[13], a32=E[14], a33=E[15];

    double s0=a00*a11-a10*a01, s1=a00*a12-a10*a02, s2=a00*a13-a10*a03;
    double s3=a01*a12-a11*a02, s4=a01*a13-a11*a03, s5=a02*a13-a12*a03;
    double c5=a22*a33-a32*a23, c4=a21*a33-a31*a23, c3=a21*a32-a31*a22;
    double c2=a20*a33-a30*a23, c1=a20*a32-a30*a22, c0=a20*a31-a30*a21;
    double det = s0*c5 - s1*c4 + s2*c3 + s3*c2 - s4*c1 + s5*c0;
    double iv = 1.0/det;

    double rot[9], trans[3];
    rot[0] = ( a11*c5 - a12*c4 + a13*c3)*iv;
    rot[1] = (-a01*c5 + a02*c4 - a03*c3)*iv;
    rot[2] = ( a31*s5 - a32*s4 + a33*s3)*iv;
    trans[0]=(-a21*s5 + a22*s4 - a23*s3)*iv;
    rot[3] = (-a10*c5 + a12*c2 - a13*c1)*iv;
    rot[4] = ( a00*c5 - a02*c2 + a03*c1)*iv;
    rot[5] = (-a30*s5 + a32*s2 - a33*s1)*iv;
    trans[1]=( a20*s5 - a22*s2 + a23*s1)*iv;
    rot[6] = ( a10*c4 - a11*c2 + a13*c0)*iv;
    rot[7] = (-a00*c4 + a01*c2 - a03*c0)*iv;
    rot[8] = ( a30*s4 - a31*s2 + a33*s0)*iv;
    trans[2]=(-a20*s4 + a21*s2 - a23*s0)*iv;

    double comb[9];
    for (int i=0;i<3;i++) for (int j=0;j<3;j++)
        comb[i*3+j] = rot[i*3+0]*kin[0+j] + rot[i*3+1]*kin[3+j] + rot[i*3+2]*kin[6+j];

    double* o = mats + (size_t)bn*MAT_STRIDE;
    for (int i=0;i<9;i++) o[i]   = prinv[i];
    for (int i=0;i<9;i++) o[9+i] = comb[i];
    for (int i=0;i<3;i++) o[18+i]= trans[i];
}

// One THREAD per point: cell id (or -1). (hist dropped — no sort in this pipeline.)
__global__ __launch_bounds__(256)
void geom_kernel(const float* __restrict__ post_trans,
                 const float* __restrict__ frustum,
                 const float* __restrict__ bev_res,
                 const float* __restrict__ bev_start,
                 const double* __restrict__ mats,
                 int* __restrict__ rank) {
    int p = blockIdx.x * blockDim.x + threadIdx.x;
    if (p >= NPTS) return;

    int w = p % W_; int t = p / W_;
    int h = t % H_;  t /= H_;
    int d = t % D_;  t /= D_;
    int bn = t;      int b = bn / N_;

    const double* M = mats + (size_t)bn*MAT_STRIDE;
    int fidx = ((d*H_ + h)*W_ + w)*3;
    double fx = (double)frustum[fidx+0];
    double fy = (double)frustum[fidx+1];
    double fz = (double)frustum[fidx+2];

    double px = fx - (double)post_trans[bn*3+0];
    double py = fy - (double)post_trans[bn*3+1];
    double pz = fz - (double)post_trans[bn*3+2];

    double q0 = M[0]*px + M[1]*py + M[2]*pz;
    double q1 = M[3]*px + M[4]*py + M[5]*pz;
    double q2 = M[6]*px + M[7]*py + M[8]*pz;

    double r0 = q0*q2, r1 = q1*q2, r2 = q2;

    double gx = M[9]*r0  + M[10]*r1 + M[11]*r2 + M[18];
    double gy = M[12]*r0 + M[13]*r1 + M[14]*r2 + M[19];
    double gz = M[15]*r0 + M[16]*r1 + M[17]*r2 + M[20];

    double resx = (double)bev_res[0], resy = (double)bev_res[1], resz = (double)bev_res[2];
    double sx = (double)bev_start[0] - resx*0.5;
    double sy = (double)bev_start[1] - resy*0.5;
    double sz = (double)bev_start[2] - resz*0.5;

    int cx = (int)((gx - sx)/resx);
    int cy = (int)((gy - sy)/resy);
    int cz = (int)((gz - sz)/resz);

    int cell = -1;
    if (cx >= 0 && cx < X_ && cy >= 0 && cy < Y_ && cz == 0)
        cell = (b*X_ + cx)*Y_ + cy;
    rank[p] = cell;
}

// Direct scatter: one wave per point (lane = channel).
// feat read SEQUENTIAL; HW f32 atomics into (B,X,Y,C)-staged accumulator
// (64 lanes -> 256B contiguous -> 4 coalesced 64B atomic lines per point).
__global__ __launch_bounds__(256)
void scatter_staged(const float* __restrict__ feat,
                    const int* __restrict__ rank,
                    float* __restrict__ stage) {
    int tid  = blockIdx.x * blockDim.x + threadIdx.x;
    int p    = tid >> 6;
    int lane = tid & 63;
    if (p >= NPTS) return;
    int cell = rank[p];                 // wave-uniform broadcast load
    if (cell < 0) return;
    float v = feat[(size_t)p*C_ + lane];
    unsafeAtomicAdd(&stage[(size_t)cell*C_ + lane], v);
}

// (B, X*Y, C) -> (B, C, X*Y) tiled transpose (verified in R0).
__global__ __launch_bounds__(512)
void transpose_kernel(const float* __restrict__ ws, float* __restrict__ out) {
    __shared__ float tile[64][65];
    int b   = blockIdx.y;
    int xy0 = blockIdx.x * 64;
    int tx  = threadIdx.x;   // 0..63
    int ty  = threadIdx.y;   // 0..7

    #pragma unroll
    for (int i=0;i<8;i++){
        int xy = xy0 + ty + i*8;
        tile[ty + i*8][tx] = ws[((size_t)b*(X_*Y_) + xy)*C_ + tx];
    }
    __syncthreads();
    #pragma unroll
    for (int i=0;i<8;i++){
        int c = ty + i*8;
        out[((size_t)(b*C_ + c))*(X_*Y_) + xy0 + tx] = tile[tx][c];
    }
}

// Fallback (tiny ws): direct atomics into (B,C,X,Y) output.
__global__ __launch_bounds__(256)
void scatter_fallback(const float* __restrict__ feat,
                      const int* __restrict__ rank,
                      float* __restrict__ dst) {
    int tid  = blockIdx.x * blockDim.x + threadIdx.x;
    int p    = tid >> 6;
    int lane = tid & 63;
    if (p >= NPTS) return;
    int cell = rank[p];
    if (cell < 0) return;
    int b = cell / (X_*Y_);
    int xy = cell % (X_*Y_);
    float v = feat[(size_t)p*C_ + lane];
    unsafeAtomicAdd(&dst[((size_t)(b*C_ + lane))*(X_*Y_) + xy], v);
}

extern "C" void kernel_launch(void* const* d_in, const int* in_sizes, int n_in,
                              void* d_out, int out_size, void* d_ws, size_t ws_size,
                              hipStream_t stream) {
    const float* feat       = (const float*)d_in[0];
    const float* post_trans = (const float*)d_in[1];
    const float* post_rots  = (const float*)d_in[2];
    const float* intr       = (const float*)d_in[3];
    const float* extr       = (const float*)d_in[4];
    const float* frustum    = (const float*)d_in[5];
    const float* bev_res    = (const float*)d_in[6];
    const float* bev_start  = (const float*)d_in[7];
    float* out = (float*)d_out;

    // ws layout
    char* base = (char*)d_ws;
    double* mats = (double*)base;                      size_t off = 4096;
    int* rank    = (int*)(base + off);                 off += (size_t)NPTS*4;
    off = (off + 511) & ~(size_t)511;
    float* stage = (float*)(base + off);               off += (size_t)NCELL*C_*4; // 20.48 MB
    bool have_ws = (ws_size >= off);

    hipLaunchKernelGGL(prep_kernel, dim3(1), dim3(16), 0, stream,
                       post_rots, intr, extr, mats);

    const int pt_blocks = (NPTS + 255) / 256;
    const int wv_blocks = ((size_t)NPTS*64 + 255) / 256;

    geom_kernel<<<pt_blocks, 256, 0, stream>>>(post_trans, frustum, bev_res,
                                               bev_start, mats, rank);

    if (have_ws) {
        hipMemsetAsync(stage, 0, (size_t)NCELL*C_*4, stream);
        scatter_staged<<<wv_blocks, 256, 0, stream>>>(feat, rank, stage);
        transpose_kernel<<<dim3((X_*Y_)/64, B_), dim3(64,8), 0, stream>>>(stage, out);
    } else {
        hipMemsetAsync(out, 0, (size_t)out_size*sizeof(float), stream);
        scatter_fallback<<<wv_blocks, 256, 0, stream>>>(feat, rank, out);
    }
}